// Round 2
// baseline (497.153 us; speedup 1.0000x reference)
//
#include <hip/hip_runtime.h>

// Problem constants (match reference)
constexpr int NB = 4, NC = 96, NH = 256, NW = 256;
constexpr int NK = 288;           // 3*NC
constexpr int HW = NH * NW;       // 65536
constexpr int RPB = 8;            // row-pairs per block
constexpr int ROWB = 640;         // y row stride bytes: mult of 128 >= 576 -> 3-bit XOR swizzle clean

typedef __attribute__((ext_vector_type(8))) short short8;   // 8 bf16 (MFMA frag)
typedef __attribute__((ext_vector_type(4))) float f32x4;    // 4 f32 acc

__device__ __forceinline__ unsigned short f2bf(float f) {
    unsigned int u = __builtin_bit_cast(unsigned int, f);
    u += 0x7FFFu + ((u >> 16) & 1u);        // round-to-nearest-even (inputs finite)
    return (unsigned short)(u >> 16);
}

__device__ __forceinline__ float ffm_sel(float a, float b) {
    return (__builtin_fabsf(a) >= __builtin_fabsf(b)) ? a : b;
}

// Light workgroup barrier: LDS hazards need lgkmcnt(0) only. Unlike __syncthreads
// (which drains vmcnt(0) too), this keeps prefetch global_loads and output stores
// in flight across the barrier. sched_barrier(0) fences per guide rule #18.
__device__ __forceinline__ void lgkm_barrier() {
    __builtin_amdgcn_sched_barrier(0);
    asm volatile("s_waitcnt lgkmcnt(0)" ::: "memory");
    __builtin_amdgcn_s_barrier();
    __builtin_amdgcn_sched_barrier(0);
}

// Fused: DWT(x1,x2,x3) -> A-avg/B/C/D-ffm -> IDWT -> concat[xr,x2,x3] -> 1x1 conv (bf16 MFMA).
// 384 thr = 6 waves; wave wv owns o-tile [16wv,16wv+16), full K=288 as 9 a-frags in registers.
// SINGLE 40,960 B LDS buffer (2 blocks/CU = 81,920 B; round-1 double buffer was an exact
// 160 KiB fit and dropped residency to 1 block/CU). Pipeline per rp: issue(rp+1) loads early,
// MFMA(rp), stores, light-barrier, stage(rp+1), light-barrier.
__global__ __launch_bounds__(384, 4) void dwt_fused_kernel(
    const float* __restrict__ x1, const float* __restrict__ x2,
    const float* __restrict__ x3, const float* __restrict__ w_out,
    float* __restrict__ out)
{
    __shared__ __align__(16) unsigned char y_lds[64 * ROWB];   // 40,960 B

    const int tid  = threadIdx.x;
    const int wv   = tid >> 6;     // 0..5 -> o-tile
    const int lane = tid & 63;
    const int n = lane & 15;       // MFMA col (=pixel) / frag row-sel
    const int q = lane >> 4;       // quad
    const int bx = blockIdx.x, by = blockIdx.y, bz = blockIdx.z;

    // ---- weights -> registers (9 bf16 a-frags = 36 VGPRs), once per block ----
    short8 wfrag[9];
    {
        const float* wr = w_out + (size_t)(16 * wv + n) * NK + 8 * q;
#pragma unroll
        for (int c9 = 0; c9 < 9; ++c9) {
            float4 lo = *(const float4*)(wr + 32 * c9);
            float4 hi = *(const float4*)(wr + 32 * c9 + 4);
            short8 f;
            f[0] = (short)f2bf(lo.x); f[1] = (short)f2bf(lo.y);
            f[2] = (short)f2bf(lo.z); f[3] = (short)f2bf(lo.w);
            f[4] = (short)f2bf(hi.x); f[5] = (short)f2bf(hi.y);
            f[6] = (short)f2bf(hi.z); f[7] = (short)f2bf(hi.w);
            wfrag[c9] = f;
        }
    }

    // staging thread mapping: channel-pair cp (0..47), col-quad cq (0..7)
    const int cp = tid >> 3;
    const int cq = tid & 7;
    const int gx = bx * 32 + 4 * cq;                 // 4 consecutive cols
    const size_t base00 = ((size_t)(bz * NC + 2 * cp) * NH + (size_t)(2 * by * RPB)) * NW + gx;
    const float* const xs[3] = {x1, x2, x3};

    float4 pf[3][2][2];                              // prefetch regs: [arr][dc][row]

    auto issue = [&](int rp) {                       // issue row-pair rp's global loads
        const size_t roff = base00 + (size_t)rp * (2 * NW);
#pragma unroll
        for (int a = 0; a < 3; ++a) {
#pragma unroll
            for (int dc = 0; dc < 2; ++dc) {
                const float* p = xs[a] + roff + (size_t)dc * HW;
                pf[a][dc][0] = *(const float4*)p;
                pf[a][dc][1] = *(const float4*)(p + NW);
            }
        }
    };

    auto stage = [&]() {                             // DWT->merge->IDWT f32, emit bf16 to swizzled LDS
        unsigned char* Y = y_lds;
#pragma unroll
        for (int hf = 0; hf < 2; ++hf) {             // which col-pair of the quad
            const int cb = 2 * cq + hf;
            float xr[2][4], r2[2][4], r3[2][4];
#pragma unroll
            for (int dc = 0; dc < 2; ++dc) {
                float2 a1, b1, a2, b2, a3, b3;
                if (hf == 0) {
                    a1 = make_float2(pf[0][dc][0].x, pf[0][dc][0].y);
                    b1 = make_float2(pf[0][dc][1].x, pf[0][dc][1].y);
                    a2 = make_float2(pf[1][dc][0].x, pf[1][dc][0].y);
                    b2 = make_float2(pf[1][dc][1].x, pf[1][dc][1].y);
                    a3 = make_float2(pf[2][dc][0].x, pf[2][dc][0].y);
                    b3 = make_float2(pf[2][dc][1].x, pf[2][dc][1].y);
                } else {
                    a1 = make_float2(pf[0][dc][0].z, pf[0][dc][0].w);
                    b1 = make_float2(pf[0][dc][1].z, pf[0][dc][1].w);
                    a2 = make_float2(pf[1][dc][0].z, pf[1][dc][0].w);
                    b2 = make_float2(pf[1][dc][1].z, pf[1][dc][1].w);
                    a3 = make_float2(pf[2][dc][0].z, pf[2][dc][0].w);
                    b3 = make_float2(pf[2][dc][1].z, pf[2][dc][1].w);
                }
                float A1, B1, C1, D1, A2, B2, C2, D2, A3, B3, C3, D3;
#define DWT4(aa, bb, Ao, Bo, Co, Do)                                          \
                { float e = aa.x * 0.5f, fE = bb.x * 0.5f,                     \
                        g = aa.y * 0.5f, hE = bb.y * 0.5f;                     \
                  Ao = ((e + fE) + g) + hE;  Bo = (((-e) - fE) + g) + hE;      \
                  Co = (((-e) + fE) - g) + hE; Do = ((e - fE) - g) + hE; }
                DWT4(a1, b1, A1, B1, C1, D1)
                DWT4(a2, b2, A2, B2, C2, D2)
                DWT4(a3, b3, A3, B3, C3, D3)
#undef DWT4
                float A  = (A1 + A2 + A3) / 3.0f;
                float Bf = ffm_sel(ffm_sel(B1, B2), B3);
                float Cf = ffm_sel(ffm_sel(C1, C2), C3);
                float Df = ffm_sel(ffm_sel(D1, D2), D3);
                xr[dc][0] = (((A - Bf) - Cf) + Df) * 0.5f;
                xr[dc][1] = (((A - Bf) + Cf) - Df) * 0.5f;
                xr[dc][2] = (((A + Bf) - Cf) - Df) * 0.5f;
                xr[dc][3] = (((A + Bf) + Cf) + Df) * 0.5f;
                r2[dc][0] = a2.x; r2[dc][1] = b2.x; r2[dc][2] = a2.y; r2[dc][3] = b2.y;
                r3[dc][0] = a3.x; r3[dc][1] = b3.x; r3[dc][2] = a3.y; r3[dc][3] = b3.y;
            }
            const int pxs[4] = {2 * cb, 32 + 2 * cb, 2 * cb + 1, 33 + 2 * cb};
#pragma unroll
            for (int p = 0; p < 4; ++p) {
                const int px = pxs[p];
                unsigned char* rowp = Y + px * ROWB;
                const int sw = ((px ^ (px >> 3)) & 7) << 4;      // 16B-block XOR swizzle
                *(ushort2*)(rowp + ((      4 * cp) ^ sw)) = make_ushort2(f2bf(xr[0][p]), f2bf(xr[1][p]));
                *(ushort2*)(rowp + ((192 + 4 * cp) ^ sw)) = make_ushort2(f2bf(r2[0][p]), f2bf(r2[1][p]));
                *(ushort2*)(rowp + ((384 + 4 * cp) ^ sw)) = make_ushort2(f2bf(r3[0][p]), f2bf(r3[1][p]));
            }
        }
    };

    // per-thread output base (o = 16wv+4q, col = bx*32+n, block row start)
    float* const outp = out + (size_t)(bz * NC + 16 * wv + 4 * q) * HW
                            + (size_t)(2 * by * RPB) * NW + bx * 32 + n;

    // ---- pipeline ----
    issue(0);
    stage();
    lgkm_barrier();

#pragma unroll 1
    for (int rp = 0; rp < RPB; ++rp) {
        if (rp + 1 < RPB) issue(rp + 1);        // loads fly during MFMA + stores

        f32x4 acc[4];
#pragma unroll
        for (int pt = 0; pt < 4; ++pt) acc[pt] = (f32x4){0.f, 0.f, 0.f, 0.f};
#pragma unroll
        for (int pt = 0; pt < 4; ++pt) {
            const int px = 16 * pt + n;
            const unsigned char* rowp = y_lds + px * ROWB;
            const int sw = ((px ^ (px >> 3)) & 7) << 4;
#pragma unroll
            for (int c9 = 0; c9 < 9; ++c9) {
                short8 bfrag = *(const short8*)(rowp + ((64 * c9 + 16 * q) ^ sw));
                acc[pt] = __builtin_amdgcn_mfma_f32_16x16x32_bf16(wfrag[c9], bfrag, acc[pt], 0, 0, 0);
            }
        }

        // epilogue: C/D col=lane&15 (px), row=quad*4+reg (o)
#pragma unroll
        for (int pt = 0; pt < 4; ++pt) {
            const int hoff = (2 * rp + (pt >> 1)) * NW + 16 * (pt & 1);
#pragma unroll
            for (int r = 0; r < 4; ++r) outp[(size_t)r * HW + hoff] = acc[pt][r];
        }

        if (rp + 1 < RPB) {
            lgkm_barrier();                     // all waves done reading y_lds
            stage();                            // consume pf, overwrite buffer
            lgkm_barrier();                     // writes visible before next reads
        }
    }
}

extern "C" void kernel_launch(void* const* d_in, const int* in_sizes, int n_in,
                              void* d_out, int out_size, void* d_ws, size_t ws_size,
                              hipStream_t stream) {
    const float* x1 = (const float*)d_in[0];
    const float* x2 = (const float*)d_in[1];
    const float* x3 = (const float*)d_in[2];
    const float* w  = (const float*)d_in[3];
    float* out = (float*)d_out;
    dim3 grid(NW / 32, NH / (2 * RPB), NB);   // 8 x 16 x 4 = 512 blocks = 2/CU
    dwt_fused_kernel<<<grid, dim3(384), 0, stream>>>(x1, x2, x3, w, out);
}

// Round 3
// 331.561 us; speedup vs baseline: 1.4994x; 1.4994x over previous
//
#include <hip/hip_runtime.h>

// Problem constants (match reference)
constexpr int NB = 4, NC = 96, NH = 256, NW = 256;
constexpr int NK = 288;           // 3*NC
constexpr int HW = NH * NW;       // 65536
constexpr int RPB = 8;            // row-pairs per block
constexpr int ROWB = 640;         // y row stride bytes: mult of 128 >= 576 -> 3-bit XOR swizzle clean

typedef __attribute__((ext_vector_type(8))) short short8;   // 8 bf16 (MFMA frag)
typedef __attribute__((ext_vector_type(4))) float f32x4;    // 4 f32 acc

__device__ __forceinline__ unsigned short f2bf(float f) {
    unsigned int u = __builtin_bit_cast(unsigned int, f);
    u += 0x7FFFu + ((u >> 16) & 1u);        // round-to-nearest-even (inputs finite)
    return (unsigned short)(u >> 16);
}

__device__ __forceinline__ float ffm_sel(float a, float b) {
    return (__builtin_fabsf(a) >= __builtin_fabsf(b)) ? a : b;
}

// Light workgroup barrier: LDS hazards need lgkmcnt(0) only. Unlike __syncthreads
// (which drains vmcnt(0) too), this keeps prefetch global_loads and output stores
// in flight across the barrier. "memory" clobber orders the compiler's real
// LDS/global ops around the asm; no sched_barrier (it pinned live ranges).
__device__ __forceinline__ void lgkm_barrier() {
    asm volatile("s_waitcnt lgkmcnt(0)" ::: "memory");
    __builtin_amdgcn_s_barrier();
}

// Fused: DWT(x1,x2,x3) -> A-avg/B/C/D-ffm -> IDWT -> concat[xr,x2,x3] -> 1x1 conv (bf16 MFMA).
// 384 thr = 6 waves; wave wv owns o-tile [16wv,16wv+16), full K=288 as 9 a-frags in registers.
// Single 40,960 B LDS buffer -> 2 blocks/CU. Pipeline per rp: issue(rp+1) loads early,
// MFMA(rp), stores, light-barrier, stage(rp+1), light-barrier.
// __launch_bounds__ 2nd arg is MIN BLOCKS/CU on this hipcc (round-2 evidence: (384,4)
// forced VGPR=64 = 24-wave cap and 470 MB of scratch spills). (384,2) -> VGPR cap 128.
__global__ __launch_bounds__(384, 2) void dwt_fused_kernel(
    const float* __restrict__ x1, const float* __restrict__ x2,
    const float* __restrict__ x3, const float* __restrict__ w_out,
    float* __restrict__ out)
{
    __shared__ __align__(16) unsigned char y_lds[64 * ROWB];   // 40,960 B

    const int tid  = threadIdx.x;
    const int wv   = tid >> 6;     // 0..5 -> o-tile
    const int lane = tid & 63;
    const int n = lane & 15;       // MFMA col (=pixel) / frag row-sel
    const int q = lane >> 4;       // quad
    const int bx = blockIdx.x, by = blockIdx.y, bz = blockIdx.z;

    // ---- weights -> registers (9 bf16 a-frags = 36 VGPRs), once per block ----
    short8 wfrag[9];
    {
        const float* wr = w_out + (size_t)(16 * wv + n) * NK + 8 * q;
#pragma unroll
        for (int c9 = 0; c9 < 9; ++c9) {
            float4 lo = *(const float4*)(wr + 32 * c9);
            float4 hi = *(const float4*)(wr + 32 * c9 + 4);
            short8 f;
            f[0] = (short)f2bf(lo.x); f[1] = (short)f2bf(lo.y);
            f[2] = (short)f2bf(lo.z); f[3] = (short)f2bf(lo.w);
            f[4] = (short)f2bf(hi.x); f[5] = (short)f2bf(hi.y);
            f[6] = (short)f2bf(hi.z); f[7] = (short)f2bf(hi.w);
            wfrag[c9] = f;
        }
    }

    // staging thread mapping: channel-pair cp (0..47), col-quad cq (0..7)
    const int cp = tid >> 3;
    const int cq = tid & 7;
    const int gx = bx * 32 + 4 * cq;                 // 4 consecutive cols
    const size_t base00 = ((size_t)(bz * NC + 2 * cp) * NH + (size_t)(2 * by * RPB)) * NW + gx;
    const float* const xs[3] = {x1, x2, x3};

    float4 pf[3][2][2];                              // prefetch regs: [arr][dc][row]

    auto issue = [&](int rp) {                       // issue row-pair rp's global loads
        const size_t roff = base00 + (size_t)rp * (2 * NW);
#pragma unroll
        for (int a = 0; a < 3; ++a) {
#pragma unroll
            for (int dc = 0; dc < 2; ++dc) {
                const float* p = xs[a] + roff + (size_t)dc * HW;
                pf[a][dc][0] = *(const float4*)p;
                pf[a][dc][1] = *(const float4*)(p + NW);
            }
        }
    };

    auto stage = [&]() {                             // DWT->merge->IDWT f32, emit bf16 to swizzled LDS
        unsigned char* Y = y_lds;
#pragma unroll
        for (int hf = 0; hf < 2; ++hf) {             // which col-pair of the quad
            const int cb = 2 * cq + hf;
            float xr[2][4], r2[2][4], r3[2][4];
#pragma unroll
            for (int dc = 0; dc < 2; ++dc) {
                float2 a1, b1, a2, b2, a3, b3;
                if (hf == 0) {
                    a1 = make_float2(pf[0][dc][0].x, pf[0][dc][0].y);
                    b1 = make_float2(pf[0][dc][1].x, pf[0][dc][1].y);
                    a2 = make_float2(pf[1][dc][0].x, pf[1][dc][0].y);
                    b2 = make_float2(pf[1][dc][1].x, pf[1][dc][1].y);
                    a3 = make_float2(pf[2][dc][0].x, pf[2][dc][0].y);
                    b3 = make_float2(pf[2][dc][1].x, pf[2][dc][1].y);
                } else {
                    a1 = make_float2(pf[0][dc][0].z, pf[0][dc][0].w);
                    b1 = make_float2(pf[0][dc][1].z, pf[0][dc][1].w);
                    a2 = make_float2(pf[1][dc][0].z, pf[1][dc][0].w);
                    b2 = make_float2(pf[1][dc][1].z, pf[1][dc][1].w);
                    a3 = make_float2(pf[2][dc][0].z, pf[2][dc][0].w);
                    b3 = make_float2(pf[2][dc][1].z, pf[2][dc][1].w);
                }
                float A1, B1, C1, D1, A2, B2, C2, D2, A3, B3, C3, D3;
#define DWT4(aa, bb, Ao, Bo, Co, Do)                                          \
                { float e = aa.x * 0.5f, fE = bb.x * 0.5f,                     \
                        g = aa.y * 0.5f, hE = bb.y * 0.5f;                     \
                  Ao = ((e + fE) + g) + hE;  Bo = (((-e) - fE) + g) + hE;      \
                  Co = (((-e) + fE) - g) + hE; Do = ((e - fE) - g) + hE; }
                DWT4(a1, b1, A1, B1, C1, D1)
                DWT4(a2, b2, A2, B2, C2, D2)
                DWT4(a3, b3, A3, B3, C3, D3)
#undef DWT4
                float A  = (A1 + A2 + A3) / 3.0f;
                float Bf = ffm_sel(ffm_sel(B1, B2), B3);
                float Cf = ffm_sel(ffm_sel(C1, C2), C3);
                float Df = ffm_sel(ffm_sel(D1, D2), D3);
                xr[dc][0] = (((A - Bf) - Cf) + Df) * 0.5f;
                xr[dc][1] = (((A - Bf) + Cf) - Df) * 0.5f;
                xr[dc][2] = (((A + Bf) - Cf) - Df) * 0.5f;
                xr[dc][3] = (((A + Bf) + Cf) + Df) * 0.5f;
                r2[dc][0] = a2.x; r2[dc][1] = b2.x; r2[dc][2] = a2.y; r2[dc][3] = b2.y;
                r3[dc][0] = a3.x; r3[dc][1] = b3.x; r3[dc][2] = a3.y; r3[dc][3] = b3.y;
            }
            const int pxs[4] = {2 * cb, 32 + 2 * cb, 2 * cb + 1, 33 + 2 * cb};
#pragma unroll
            for (int p = 0; p < 4; ++p) {
                const int px = pxs[p];
                unsigned char* rowp = Y + px * ROWB;
                const int sw = ((px ^ (px >> 3)) & 7) << 4;      // 16B-block XOR swizzle
                *(ushort2*)(rowp + ((      4 * cp) ^ sw)) = make_ushort2(f2bf(xr[0][p]), f2bf(xr[1][p]));
                *(ushort2*)(rowp + ((192 + 4 * cp) ^ sw)) = make_ushort2(f2bf(r2[0][p]), f2bf(r2[1][p]));
                *(ushort2*)(rowp + ((384 + 4 * cp) ^ sw)) = make_ushort2(f2bf(r3[0][p]), f2bf(r3[1][p]));
            }
        }
    };

    // per-thread output base (o = 16wv+4q, col = bx*32+n, block row start)
    float* const outp = out + (size_t)(bz * NC + 16 * wv + 4 * q) * HW
                            + (size_t)(2 * by * RPB) * NW + bx * 32 + n;

    // ---- pipeline ----
    issue(0);
    stage();
    lgkm_barrier();

#pragma unroll 1
    for (int rp = 0; rp < RPB; ++rp) {
        if (rp + 1 < RPB) issue(rp + 1);        // loads fly during MFMA + stores

        f32x4 acc[4];
#pragma unroll
        for (int pt = 0; pt < 4; ++pt) acc[pt] = (f32x4){0.f, 0.f, 0.f, 0.f};
#pragma unroll
        for (int pt = 0; pt < 4; ++pt) {
            const int px = 16 * pt + n;
            const unsigned char* rowp = y_lds + px * ROWB;
            const int sw = ((px ^ (px >> 3)) & 7) << 4;
#pragma unroll
            for (int c9 = 0; c9 < 9; ++c9) {
                short8 bfrag = *(const short8*)(rowp + ((64 * c9 + 16 * q) ^ sw));
                acc[pt] = __builtin_amdgcn_mfma_f32_16x16x32_bf16(wfrag[c9], bfrag, acc[pt], 0, 0, 0);
            }
        }

        // epilogue: C/D col=lane&15 (px), row=quad*4+reg (o)
#pragma unroll
        for (int pt = 0; pt < 4; ++pt) {
            const int hoff = (2 * rp + (pt >> 1)) * NW + 16 * (pt & 1);
#pragma unroll
            for (int r = 0; r < 4; ++r) outp[(size_t)r * HW + hoff] = acc[pt][r];
        }

        if (rp + 1 < RPB) {
            lgkm_barrier();                     // all waves done reading y_lds
            stage();                            // consume pf, overwrite buffer
            lgkm_barrier();                     // writes visible before next reads
        }
    }
}

extern "C" void kernel_launch(void* const* d_in, const int* in_sizes, int n_in,
                              void* d_out, int out_size, void* d_ws, size_t ws_size,
                              hipStream_t stream) {
    const float* x1 = (const float*)d_in[0];
    const float* x2 = (const float*)d_in[1];
    const float* x3 = (const float*)d_in[2];
    const float* w  = (const float*)d_in[3];
    float* out = (float*)d_out;
    dim3 grid(NW / 32, NH / (2 * RPB), NB);   // 8 x 16 x 4 = 512 blocks = 2/CU
    dwt_fused_kernel<<<grid, dim3(384), 0, stream>>>(x1, x2, x3, w, out);
}